// Round 1
// baseline (94.987 us; speedup 1.0000x reference)
//
#include <hip/hip_runtime.h>

// Circular (wrap) padding: (64,256,256,16) f32 -> (64,260,260,16) f32, pad=2
// on the two spatial dims. Pure memory-bound gather; one thread per float4
// (4 channels), 16B/lane coalesced loads and stores.

constexpr int B  = 64;
constexpr int H  = 256;
constexpr int W  = 256;
constexpr int C  = 16;
constexpr int P  = 2;
constexpr int HO = H + 2 * P;   // 260
constexpr int WO = W + 2 * P;   // 260
constexpr int C4 = C / 4;       // 4 float4s per pixel

constexpr int N_OUT4 = B * HO * WO * C4;  // 17,305,600 float4 elements

__global__ __launch_bounds__(256) void periodic_pad_kernel(
    const float4* __restrict__ in, float4* __restrict__ out) {
    int idx = blockIdx.x * blockDim.x + threadIdx.x;
    if (idx >= N_OUT4) return;

    // idx = ((b*HO + oh)*WO + ow)*C4 + c4  (channels innermost)
    int c4 = idx & (C4 - 1);
    int t  = idx >> 2;          // /C4
    int ow = t % WO;
    t      = t / WO;
    int oh = t % HO;
    int b  = t / HO;

    int ih = oh - P;
    if (ih < 0) ih += H; else if (ih >= H) ih -= H;
    int iw = ow - P;
    if (iw < 0) iw += W; else if (iw >= W) iw -= W;

    int iidx = ((b * H + ih) * W + iw) * C4 + c4;
    out[idx] = in[iidx];
}

extern "C" void kernel_launch(void* const* d_in, const int* in_sizes, int n_in,
                              void* d_out, int out_size, void* d_ws, size_t ws_size,
                              hipStream_t stream) {
    const float4* in  = (const float4*)d_in[0];
    float4*       out = (float4*)d_out;

    const int block = 256;
    const int grid  = (N_OUT4 + block - 1) / block;  // 67,600 blocks
    periodic_pad_kernel<<<grid, block, 0, stream>>>(in, out);
}

// Round 4
// 82.260 us; speedup vs baseline: 1.1547x; 1.1547x over previous
//
#include <hip/hip_runtime.h>

// Circular (wrap) padding: (64,256,256,16) f32 -> (64,260,260,16) f32, pad=2.
// Memory-bound gather. One thread handles 4 INDEPENDENT float4s spaced by the
// full thread count (keeps each access wave-coalesced at 16B/lane while giving
// 4-deep memory-level parallelism per thread). Grid is sized so coverage is
// exact: N_OUT4 = 256 threads * 16900 blocks * 4 — no bounds checks, no loop.
// Uses clang ext_vector float4 (not HIP_vector_type) so
// __builtin_nontemporal_store accepts it.

typedef float f4 __attribute__((ext_vector_type(4)));

constexpr int B  = 64;
constexpr int H  = 256;
constexpr int W  = 256;
constexpr int C  = 16;
constexpr int P  = 2;
constexpr int HO = H + 2 * P;   // 260
constexpr int WO = W + 2 * P;   // 260
constexpr int C4 = C / 4;       // 4 float4s per pixel

constexpr int N_OUT4  = B * HO * WO * C4;   // 17,305,600
constexpr int BLOCK   = 256;
constexpr int UNROLL  = 4;
constexpr int GRID    = N_OUT4 / (BLOCK * UNROLL);   // 16,900 exactly
constexpr int STRIDE  = BLOCK * GRID;                // 4,326,400

__device__ __forceinline__ int src_index(int idx) {
    // idx = ((b*HO + oh)*WO + ow)*C4 + c4   (channels innermost)
    int c4 = idx & (C4 - 1);
    int t  = idx >> 2;          // / C4
    int ow = t % WO;
    t      = t / WO;
    int oh = t % HO;
    int b  = t / HO;

    int ih = oh - P;
    if (ih < 0) ih += H; else if (ih >= H) ih -= H;
    int iw = ow - P;
    if (iw < 0) iw += W; else if (iw >= W) iw -= W;

    return ((b * H + ih) * W + iw) * C4 + c4;
}

__global__ __launch_bounds__(BLOCK) void periodic_pad_kernel(
    const f4* __restrict__ in, f4* __restrict__ out) {
    const int tid = blockIdx.x * BLOCK + threadIdx.x;

    f4 v[UNROLL];
#pragma unroll
    for (int u = 0; u < UNROLL; ++u) {
        const int idx = tid + u * STRIDE;
        v[u] = in[src_index(idx)];
    }
#pragma unroll
    for (int u = 0; u < UNROLL; ++u) {
        const int idx = tid + u * STRIDE;
        __builtin_nontemporal_store(v[u], &out[idx]);
    }
}

extern "C" void kernel_launch(void* const* d_in, const int* in_sizes, int n_in,
                              void* d_out, int out_size, void* d_ws, size_t ws_size,
                              hipStream_t stream) {
    const f4* in  = (const f4*)d_in[0];
    f4*       out = (f4*)d_out;
    periodic_pad_kernel<<<GRID, BLOCK, 0, stream>>>(in, out);
}